// Round 16
// baseline (170.259 us; speedup 1.0000x reference)
//
#include <hip/hip_runtime.h>

#define NB 256
#define NA 64
#define NG 978
#define CELL_IN 978
#define DOSE_IN 12
#define GLOBAL_F 306
#define EXP_IN 434
#define NE 4

// ---- workspace layout (float offsets) ----
#define WS_SEL 0                       // [256][4]
#define WS_U   (WS_SEL + NB*4)         // [256][2][128]
#define WS_V   (WS_U + NB*256)         // [16][512][64]
#define WS_P1  (WS_V + 16*512*64)      // [4][256][200] cell1 K-partials
// total ~796k floats ~3.0 MB

#define A_BLOCKS 256
#define AB_GRID  (NB + A_BLOCKS)       // 512 blocks -> 2 blocks/CU

__device__ __forceinline__ float wave_reduce(float p) {
    #pragma unroll
    for (int off = 32; off > 0; off >>= 1) p += __shfl_down(p, off, 64);
    return p;
}

// ---------------------------------------------------------------------------
// K0: cell1 batch-tiled GEMM partials.
// grid = 128 blocks = (16 batch-tiles x 2 output-halves x 4 K-quarters).
// Each cW1 stripe is read by 16 blocks instead of 256 -> 16x traffic cut.
// part[q][b][j] = sum_{k in Kq} gex[b][k] * cW1[k][j]
// ---------------------------------------------------------------------------
__global__ __launch_bounds__(1024) void cell1_kernel(
    const float* __restrict__ gex, const float* __restrict__ cW1,
    float* __restrict__ ws)
{
    __shared__ float s_x[16][248];     // 16 batches x K-quarter (padded)
    const int blk = blockIdx.x, tid = threadIdx.x;
    const int m = blk >> 3, n = (blk >> 2) & 1, q = blk & 3;
    const int b0 = m * 16, j0 = n * 100, k0 = q * 245;
    const int klen = (q == 3) ? 243 : 245;

    {   // stage gex tile: wave r loads row r (coalesced)
        int r = tid >> 6, lane = tid & 63;
        for (int kk = lane; kk < klen; kk += 64)
            s_x[r][kk] = gex[(size_t)(b0 + r) * CELL_IN + k0 + kk];
    }
    __syncthreads();

    const int r = tid >> 6, lane = tid & 63;
    if (lane < 25) {
        const float* wp = cW1 + (size_t)k0 * 200 + j0 + 4 * lane;
        float4 acc = {0.f, 0.f, 0.f, 0.f};
        #pragma unroll 4
        for (int i = 0; i < klen; ++i) {
            float x = s_x[r][i];                    // wave-uniform broadcast
            float4 w = *(const float4*)(wp + (size_t)i * 200);
            acc.x += x * w.x; acc.y += x * w.y; acc.z += x * w.z; acc.w += x * w.w;
        }
        *(float4*)(ws + WS_P1 + ((size_t)(q * NB + b0 + r)) * 200 + j0 + 4 * lane) = acc;
    }
}

// ---------------------------------------------------------------------------
// AB: blocks [0,256): b-pipeline (r12 verbatim, P1-compute replaced by a
//     4-partial reduction from ws; gex staging removed).
//     blocks [256,512): v_t producer (r12 verbatim).
// ---------------------------------------------------------------------------
__global__ __launch_bounds__(1024) void ab_kernel(
    const float* __restrict__ drug, const float* __restrict__ idose,
    const float* __restrict__ cb1,
    const float* __restrict__ cW2, const float* __restrict__ cb2,
    const float* __restrict__ cW3, const float* __restrict__ cb3,
    const float* __restrict__ dW1, const float* __restrict__ db1,
    const float* __restrict__ dW2, const float* __restrict__ db2,
    const float* __restrict__ gW1, const float* __restrict__ gb1,
    const float* __restrict__ gW2, const float* __restrict__ gb2,
    const float* __restrict__ eW1, const float* __restrict__ eb1,
    const float* __restrict__ gene,
    float* __restrict__ ws, float* __restrict__ cell_out)
{
    __shared__ float s_g[GLOBAL_F];
    __shared__ float s_h1[200];
    __shared__ float s_h2[100];
    __shared__ float s_gh[128];
    __shared__ float s_d1[64];
    __shared__ int   s_isel[2];
    __shared__ float s_part[16 * 200];
    __shared__ float s_pu[32 * 128];
    __shared__ float s_gene[64 * 129];   // a-part only (padded)

    const int blk = blockIdx.x, tid = threadIdx.x;

    if (blk >= NB) {
        // ===== a-part: v_t[tile][e*128+h][g_in], (tile,e,hq) per block =====
        const int ablk = blk - NB;
        const int tile = ablk >> 4, e = (ablk >> 2) & 3, hq = ablk & 3;

        for (int i = tid; i < 64 * 128; i += 1024) {
            int gl = i >> 7, k = i & 127;
            int g = tile * 64 + gl;
            s_gene[gl * 129 + k] = (g < NG) ? gene[g * 128 + k] : 0.f;
        }
        __syncthreads();

        const int slice = tid >> 6, g_in = tid & 63;
        const int h0 = hq * 32 + slice * 2;
        const float* wbase = eW1 + ((size_t)e * EXP_IN + GLOBAL_F) * 128 + h0;
        float a0 = 0.f, a1 = 0.f;
        #pragma unroll 8
        for (int k = 0; k < 128; ++k) {
            float x = s_gene[g_in * 129 + k];
            float2 w = *(const float2*)(wbase + (size_t)k * 128);
            a0 += x * w.x; a1 += x * w.y;
        }
        float* vout = ws + WS_V + ((size_t)tile * 512 + e * 128 + h0) * 64 + g_in;
        vout[0]  = a0;
        vout[64] = a1;
        return;
    }

    // ==================== b-part: per-batch pipeline =======================
    const int b = blk;

    // ---- P0: drug partials; dose layer1 ----
    {
        int row = tid >> 7, d = tid & 127;
        const float* p = drug + ((size_t)b * NA) * 128 + d;
        float acc = 0.f;
        #pragma unroll
        for (int i = 0; i < 8; ++i) acc += p[(size_t)(i * 8 + row) * 128];
        s_pu[row * 128 + d] = acc;
    }
    __syncthreads();
    if (tid < 128) {
        float a = 0.f;
        #pragma unroll
        for (int r = 0; r < 8; ++r) a += s_pu[r * 128 + tid];
        s_g[tid] = a;
    } else if (tid < 192) {
        int j = tid - 128;
        float acc = db1[j];
        #pragma unroll
        for (int i = 0; i < DOSE_IN; ++i)
            acc += idose[b * DOSE_IN + i] * dW1[i * 64 + j];
        s_d1[j] = fmaxf(acc, 0.f);
    }
    __syncthreads();
    if (tid < 128) {
        float acc = db2[tid];
        #pragma unroll 8
        for (int i = 0; i < 64; ++i) acc += s_d1[i] * dW2[i * 128 + tid];
        s_g[178 + tid] = fmaxf(acc, 0.f);
    }

    // ---- P1': h1 from ws partials (cell1_kernel ran in prior dispatch) ----
    if (tid >= 256 && tid < 456) {
        int j = tid - 256;
        float a = cb1[j]
                + ws[WS_P1 + ((size_t)(0 * NB + b)) * 200 + j]
                + ws[WS_P1 + ((size_t)(1 * NB + b)) * 200 + j]
                + ws[WS_P1 + ((size_t)(2 * NB + b)) * 200 + j]
                + ws[WS_P1 + ((size_t)(3 * NB + b)) * 200 + j];
        s_h1[j] = fmaxf(a, 0.f);
    }
    __syncthreads();

    // ---- P2: cell2 200->100, 16-way K-split, float4 ----
    {
        int q = tid & 31, ks = tid >> 5;
        if (q < 25 && ks < 16) {
            int i0 = ks * 13, i1 = min(i0 + 13, 200);
            float4 acc = {0.f, 0.f, 0.f, 0.f};
            #pragma unroll
            for (int i = i0; i < i1; ++i) {
                float4 w = *(const float4*)(cW2 + (size_t)i * 100 + 4 * q);
                float x = s_h1[i];
                acc.x += x * w.x; acc.y += x * w.y; acc.z += x * w.z; acc.w += x * w.w;
            }
            *(float4*)(&s_part[ks * 100 + 4 * q]) = acc;
        }
    }
    __syncthreads();
    if (tid < 100) {
        float a = cb2[tid];
        #pragma unroll
        for (int ks = 0; ks < 16; ++ks) a += s_part[ks * 100 + tid];
        s_h2[tid] = fmaxf(a, 0.f);
    }
    __syncthreads();

    // ---- P3: cell3 100->50, 8-way K-split ----
    {
        int j = tid & 63, ks = tid >> 6;
        if (j < 50 && ks < 8) {
            int i0 = ks * 13, i1 = min(i0 + 13, 100);
            float acc = 0.f;
            #pragma unroll
            for (int i = i0; i < i1; ++i) acc += s_h2[i] * cW3[i * 50 + j];
            s_part[ks * 64 + j] = acc;
        }
    }
    __syncthreads();
    if (tid < 50) {
        float a = cb3[tid];
        #pragma unroll
        for (int ks = 0; ks < 8; ++ks) a += s_part[ks * 64 + tid];
        float r = fmaxf(a, 0.f);
        s_g[128 + tid] = r;
        cell_out[b * 50 + tid] = r;
    }
    __syncthreads();

    // ---- P4: gate1 306->128, 16-way K-split, float4 ----
    {
        int q = tid & 31, ks = tid >> 5;
        if (ks < 16) {
            int i0 = ks * 20, i1 = min(i0 + 20, GLOBAL_F);
            float4 acc = {0.f, 0.f, 0.f, 0.f};
            #pragma unroll
            for (int i = i0; i < i1; ++i) {
                float4 w = *(const float4*)(gW1 + (size_t)i * 128 + 4 * q);
                float x = s_g[i];
                acc.x += x * w.x; acc.y += x * w.y; acc.z += x * w.z; acc.w += x * w.w;
            }
            *(float4*)(&s_part[ks * 128 + 4 * q]) = acc;
        }
    }
    __syncthreads();
    if (tid < 128) {
        float a = gb1[tid];
        #pragma unroll
        for (int ks = 0; ks < 16; ++ks) a += s_part[ks * 128 + tid];
        s_gh[tid] = fmaxf(a, 0.f);
    }
    __syncthreads();

    // ---- P5: logits + top-2 softmax -> s_isel, ws sel ----
    if (tid < 64) {
        float h0 = s_gh[tid], h1 = s_gh[tid + 64];
        float logit[NE];
        #pragma unroll
        for (int j = 0; j < NE; ++j) {
            float p = h0 * gW2[tid * NE + j] + h1 * gW2[(tid + 64) * NE + j];
            p = wave_reduce(p);
            logit[j] = p + gb2[j];
        }
        if (tid == 0) {
            int i1 = 0; float v1 = logit[0];
            #pragma unroll
            for (int i = 1; i < NE; ++i) if (logit[i] > v1) { v1 = logit[i]; i1 = i; }
            int i2 = -1; float v2 = -__builtin_inff();
            #pragma unroll
            for (int i = 0; i < NE; ++i) {
                if (i == i1) continue;
                if (logit[i] > v2) { v2 = logit[i]; i2 = i; }
            }
            float ex = __expf(v2 - v1);
            float inv = 1.f / (1.f + ex);
            s_isel[0] = i1; s_isel[1] = i2;
            ws[WS_SEL + b * 4 + 0] = (float)i1;
            ws[WS_SEL + b * 4 + 1] = (float)i2;
            ws[WS_SEL + b * 4 + 2] = inv;
            ws[WS_SEL + b * 4 + 3] = ex * inv;
        }
    }
    __syncthreads();

    // ---- P6: u for the 2 ACTIVE experts, 16-way K-split, float4 ----
    {
        int es = tid >> 9, ks = (tid >> 5) & 15, h4 = tid & 31;
        int e = s_isel[es];
        int i0 = ks * 20, i1 = min(i0 + 20, GLOBAL_F);
        const float* wp = eW1 + (size_t)e * EXP_IN * 128 + 4 * h4;
        float4 acc = {0.f, 0.f, 0.f, 0.f};
        #pragma unroll
        for (int i = i0; i < i1; ++i) {
            float4 w = *(const float4*)(wp + (size_t)i * 128);
            float x = s_g[i];
            acc.x += x * w.x; acc.y += x * w.y; acc.z += x * w.z; acc.w += x * w.w;
        }
        *(float4*)(&s_pu[(es * 16 + ks) * 128 + 4 * h4]) = acc;
    }
    __syncthreads();
    if (tid < 256) {
        int es = tid >> 7, h = tid & 127;
        int e = s_isel[es];
        float a = eb1[e * 128 + h];
        #pragma unroll
        for (int ks = 0; ks < 16; ++ks) a += s_pu[(es * 16 + ks) * 128 + h];
        ws[WS_U + (size_t)b * 256 + es * 128 + h] = a;
    }
}

// ---------------------------------------------------------------------------
// C: epilogue over transposed v (proven r12 design).
// ---------------------------------------------------------------------------
__global__ __launch_bounds__(256) void c_kernel(
    const float* __restrict__ eW2, const float* __restrict__ eb2,
    const float* __restrict__ ws, float* __restrict__ pred)
{
    __shared__ float s_u[256];
    __shared__ float s_w2[256];
    const int b = blockIdx.x >> 2, quad = blockIdx.x & 3, tid = threadIdx.x;

    const int ea = (int)ws[WS_SEL + b * 4 + 0];
    const int eb = (int)ws[WS_SEL + b * 4 + 1];
    const float gA = ws[WS_SEL + b * 4 + 2];
    const float gB = ws[WS_SEL + b * 4 + 3];
    const float bA = eb2[ea], bB = eb2[eb];

    s_u[tid] = ws[WS_U + (size_t)b * 256 + tid];
    s_w2[tid] = (tid < 128) ? eW2[ea * 128 + tid] : eW2[eb * 128 + (tid - 128)];
    __syncthreads();

    const int wv = tid >> 6, lane = tid & 63;
    const int tile = quad * 4 + wv;
    const float* vA = ws + WS_V + ((size_t)tile * 512 + ea * 128) * 64 + lane;
    const float* vB = ws + WS_V + ((size_t)tile * 512 + eb * 128) * 64 + lane;

    float dA = 0.f, dB = 0.f;
    #pragma unroll 8
    for (int h = 0; h < 128; ++h) {
        dA += fmaxf(s_u[h]       + vA[(size_t)h * 64], 0.f) * s_w2[h];
        dB += fmaxf(s_u[128 + h] + vB[(size_t)h * 64], 0.f) * s_w2[128 + h];
    }
    const int g = tile * 64 + lane;
    if (g < NG) pred[(size_t)b * NG + g] = gA * (dA + bA) + gB * (dB + bB);
}

// ---------------------------------------------------------------------------
extern "C" void kernel_launch(void* const* d_in, const int* in_sizes, int n_in,
                              void* d_out, int out_size, void* d_ws, size_t ws_size,
                              hipStream_t stream) {
    const float* drug  = (const float*)d_in[0];
    const float* gex   = (const float*)d_in[1];
    const float* idose = (const float*)d_in[2];
    const float* cW1 = (const float*)d_in[3];  const float* cb1 = (const float*)d_in[4];
    const float* cW2 = (const float*)d_in[5];  const float* cb2 = (const float*)d_in[6];
    const float* cW3 = (const float*)d_in[7];  const float* cb3 = (const float*)d_in[8];
    const float* dW1 = (const float*)d_in[9];  const float* db1 = (const float*)d_in[10];
    const float* dW2 = (const float*)d_in[11]; const float* db2 = (const float*)d_in[12];
    const float* gene = (const float*)d_in[13];
    const float* gW1 = (const float*)d_in[14]; const float* gb1 = (const float*)d_in[15];
    const float* gW2 = (const float*)d_in[16]; const float* gb2 = (const float*)d_in[17];
    const float* eW1 = (const float*)d_in[18]; const float* eb1 = (const float*)d_in[19];
    const float* eW2 = (const float*)d_in[20]; const float* eb2 = (const float*)d_in[21];

    float* ws   = (float*)d_ws;
    float* out  = (float*)d_out;
    float* pred = out;               // [B, G]
    float* cell = out + NB * NG;     // [B, 50]

    cell1_kernel<<<128, 1024, 0, stream>>>(gex, cW1, ws);
    ab_kernel<<<AB_GRID, 1024, 0, stream>>>(drug, idose, cb1,
        cW2, cb2, cW3, cb3, dW1, db1, dW2, db2,
        gW1, gb1, gW2, gb2, eW1, eb1, gene, ws, cell);
    c_kernel<<<NB * 4, 256, 0, stream>>>(eW2, eb2, ws, pred);
}

// Round 17
// 152.227 us; speedup vs baseline: 1.1185x; 1.1185x over previous
//
#include <hip/hip_runtime.h>

#define NB 256
#define NA 64
#define NG 978
#define CELL_IN 978
#define DOSE_IN 12
#define GLOBAL_F 306
#define EXP_IN 434
#define NE 4

// ---- workspace layout (float offsets) ----
// v is stored GENE-TRANSPOSED: v_t[tile][e*128+h][64]  (16 tiles of 64 genes)
#define WS_SEL 0                       // [256][4] : e1, e2, gate1, gate2
#define WS_U   (WS_SEL + NB*4)         // [256][2][128]
#define WS_V   (WS_U + NB*256)         // [16][512][64] = 524288 floats

#define A_BLOCKS 256                   // 16 tiles x 4 experts x 4 h-quarters
#define AB_GRID  (NB + A_BLOCKS)       // 512 blocks -> 2 blocks/CU everywhere

__device__ __forceinline__ float wave_reduce(float p) {
    #pragma unroll
    for (int off = 32; off > 0; off >>= 1) p += __shfl_down(p, off, 64);
    return p;
}

// ---------------------------------------------------------------------------
// AB: blocks [0,256): per-batch pipeline. blocks [256,512): v_t producer.
// r12 configuration verbatim — measured best (150.1 us).
// ---------------------------------------------------------------------------
__global__ __launch_bounds__(1024) void ab_kernel(
    const float* __restrict__ drug, const float* __restrict__ gex,
    const float* __restrict__ idose,
    const float* __restrict__ cW1, const float* __restrict__ cb1,
    const float* __restrict__ cW2, const float* __restrict__ cb2,
    const float* __restrict__ cW3, const float* __restrict__ cb3,
    const float* __restrict__ dW1, const float* __restrict__ db1,
    const float* __restrict__ dW2, const float* __restrict__ db2,
    const float* __restrict__ gW1, const float* __restrict__ gb1,
    const float* __restrict__ gW2, const float* __restrict__ gb2,
    const float* __restrict__ eW1, const float* __restrict__ eb1,
    const float* __restrict__ gene,
    float* __restrict__ ws, float* __restrict__ cell_out)
{
    __shared__ float s_gex[CELL_IN];
    __shared__ float s_g[GLOBAL_F];
    __shared__ float s_h1[200];
    __shared__ float s_h2[100];
    __shared__ float s_gh[128];
    __shared__ float s_d1[64];
    __shared__ int   s_isel[2];
    __shared__ float s_part[16 * 200];
    __shared__ float s_pu[32 * 128];
    __shared__ float s_gene[64 * 129];   // a-part only (padded)

    const int blk = blockIdx.x, tid = threadIdx.x;

    if (blk >= NB) {
        // ===== a-part: v_t[tile][e*128+h][g_in], (tile,e,hq) per block =====
        const int ablk = blk - NB;                 // 0..255
        const int tile = ablk >> 4, e = (ablk >> 2) & 3, hq = ablk & 3;

        for (int i = tid; i < 64 * 128; i += 1024) {
            int gl = i >> 7, k = i & 127;
            int g = tile * 64 + gl;
            s_gene[gl * 129 + k] = (g < NG) ? gene[g * 128 + k] : 0.f;
        }
        __syncthreads();

        const int slice = tid >> 6, g_in = tid & 63;   // 16 slices x 64 genes
        const int h0 = hq * 32 + slice * 2;            // 2 h-values per thread
        const float* wbase = eW1 + ((size_t)e * EXP_IN + GLOBAL_F) * 128 + h0;
        float a0 = 0.f, a1 = 0.f;
        #pragma unroll 8
        for (int k = 0; k < 128; ++k) {
            float x = s_gene[g_in * 129 + k];          // padded: conflict-free
            float2 w = *(const float2*)(wbase + (size_t)k * 128);
            a0 += x * w.x; a1 += x * w.y;
        }
        float* vout = ws + WS_V + ((size_t)tile * 512 + e * 128 + h0) * 64 + g_in;
        vout[0]  = a0;                                 // lane=gene: coalesced
        vout[64] = a1;
        return;
    }

    // ==================== b-part: per-batch pipeline =======================
    const int b = blk;

    // ---- P0: stage gex; drug partials; dose layer1 ----
    if (tid < CELL_IN) s_gex[tid] = gex[b * CELL_IN + tid];
    {
        int row = tid >> 7, d = tid & 127;
        const float* p = drug + ((size_t)b * NA) * 128 + d;
        float acc = 0.f;
        #pragma unroll
        for (int i = 0; i < 8; ++i) acc += p[(size_t)(i * 8 + row) * 128];
        s_pu[row * 128 + d] = acc;
    }
    __syncthreads();
    if (tid < 128) {
        float a = 0.f;
        #pragma unroll
        for (int r = 0; r < 8; ++r) a += s_pu[r * 128 + tid];
        s_g[tid] = a;
    } else if (tid < 192) {
        int j = tid - 128;
        float acc = db1[j];
        #pragma unroll
        for (int i = 0; i < DOSE_IN; ++i)
            acc += idose[b * DOSE_IN + i] * dW1[i * 64 + j];
        s_d1[j] = fmaxf(acc, 0.f);
    }
    __syncthreads();
    if (tid < 128) {
        float acc = db2[tid];
        #pragma unroll 8
        for (int i = 0; i < 64; ++i) acc += s_d1[i] * dW2[i * 128 + tid];
        s_g[178 + tid] = fmaxf(acc, 0.f);
    }
    __syncthreads();

    // ---- P1: cell1 978->200, 16-way K-split, float4 ----
    {
        int q = tid & 63, ks = tid >> 6;
        if (q < 50) {
            int i0 = ks * 62, i1 = min(i0 + 62, CELL_IN);
            float4 acc = {0.f, 0.f, 0.f, 0.f};
            #pragma unroll 4
            for (int i = i0; i < i1; ++i) {
                float4 w = *(const float4*)(cW1 + (size_t)i * 200 + 4 * q);
                float x = s_gex[i];
                acc.x += x * w.x; acc.y += x * w.y; acc.z += x * w.z; acc.w += x * w.w;
            }
            *(float4*)(&s_part[ks * 200 + 4 * q]) = acc;
        }
    }
    __syncthreads();
    if (tid < 200) {
        float a = cb1[tid];
        #pragma unroll
        for (int ks = 0; ks < 16; ++ks) a += s_part[ks * 200 + tid];
        s_h1[tid] = fmaxf(a, 0.f);
    }
    __syncthreads();

    // ---- P2: cell2 200->100, 16-way K-split, float4 ----
    {
        int q = tid & 31, ks = tid >> 5;
        if (q < 25 && ks < 16) {
            int i0 = ks * 13, i1 = min(i0 + 13, 200);
            float4 acc = {0.f, 0.f, 0.f, 0.f};
            #pragma unroll
            for (int i = i0; i < i1; ++i) {
                float4 w = *(const float4*)(cW2 + (size_t)i * 100 + 4 * q);
                float x = s_h1[i];
                acc.x += x * w.x; acc.y += x * w.y; acc.z += x * w.z; acc.w += x * w.w;
            }
            *(float4*)(&s_part[ks * 100 + 4 * q]) = acc;
        }
    }
    __syncthreads();
    if (tid < 100) {
        float a = cb2[tid];
        #pragma unroll
        for (int ks = 0; ks < 16; ++ks) a += s_part[ks * 100 + tid];
        s_h2[tid] = fmaxf(a, 0.f);
    }
    __syncthreads();

    // ---- P3: cell3 100->50, 8-way K-split ----
    {
        int j = tid & 63, ks = tid >> 6;
        if (j < 50 && ks < 8) {
            int i0 = ks * 13, i1 = min(i0 + 13, 100);
            float acc = 0.f;
            #pragma unroll
            for (int i = i0; i < i1; ++i) acc += s_h2[i] * cW3[i * 50 + j];
            s_part[ks * 64 + j] = acc;
        }
    }
    __syncthreads();
    if (tid < 50) {
        float a = cb3[tid];
        #pragma unroll
        for (int ks = 0; ks < 8; ++ks) a += s_part[ks * 64 + tid];
        float r = fmaxf(a, 0.f);
        s_g[128 + tid] = r;
        cell_out[b * 50 + tid] = r;
    }
    __syncthreads();

    // ---- P4: gate1 306->128, 16-way K-split, float4 ----
    {
        int q = tid & 31, ks = tid >> 5;
        if (ks < 16) {
            int i0 = ks * 20, i1 = min(i0 + 20, GLOBAL_F);
            float4 acc = {0.f, 0.f, 0.f, 0.f};
            #pragma unroll
            for (int i = i0; i < i1; ++i) {
                float4 w = *(const float4*)(gW1 + (size_t)i * 128 + 4 * q);
                float x = s_g[i];
                acc.x += x * w.x; acc.y += x * w.y; acc.z += x * w.z; acc.w += x * w.w;
            }
            *(float4*)(&s_part[ks * 128 + 4 * q]) = acc;
        }
    }
    __syncthreads();
    if (tid < 128) {
        float a = gb1[tid];
        #pragma unroll
        for (int ks = 0; ks < 16; ++ks) a += s_part[ks * 128 + tid];
        s_gh[tid] = fmaxf(a, 0.f);
    }
    __syncthreads();

    // ---- P5: logits + top-2 softmax -> s_isel, ws sel ----
    if (tid < 64) {
        float h0 = s_gh[tid], h1 = s_gh[tid + 64];
        float logit[NE];
        #pragma unroll
        for (int j = 0; j < NE; ++j) {
            float p = h0 * gW2[tid * NE + j] + h1 * gW2[(tid + 64) * NE + j];
            p = wave_reduce(p);
            logit[j] = p + gb2[j];
        }
        if (tid == 0) {
            int i1 = 0; float v1 = logit[0];
            #pragma unroll
            for (int i = 1; i < NE; ++i) if (logit[i] > v1) { v1 = logit[i]; i1 = i; }
            int i2 = -1; float v2 = -__builtin_inff();
            #pragma unroll
            for (int i = 0; i < NE; ++i) {
                if (i == i1) continue;
                if (logit[i] > v2) { v2 = logit[i]; i2 = i; }
            }
            float ex = __expf(v2 - v1);
            float inv = 1.f / (1.f + ex);
            s_isel[0] = i1; s_isel[1] = i2;
            ws[WS_SEL + b * 4 + 0] = (float)i1;
            ws[WS_SEL + b * 4 + 1] = (float)i2;
            ws[WS_SEL + b * 4 + 2] = inv;
            ws[WS_SEL + b * 4 + 3] = ex * inv;
        }
    }
    __syncthreads();

    // ---- P6: u for the 2 ACTIVE experts, 16-way K-split, float4 ----
    {
        int es = tid >> 9, ks = (tid >> 5) & 15, h4 = tid & 31;
        int e = s_isel[es];
        int i0 = ks * 20, i1 = min(i0 + 20, GLOBAL_F);
        const float* wp = eW1 + (size_t)e * EXP_IN * 128 + 4 * h4;
        float4 acc = {0.f, 0.f, 0.f, 0.f};
        #pragma unroll
        for (int i = i0; i < i1; ++i) {
            float4 w = *(const float4*)(wp + (size_t)i * 128);
            float x = s_g[i];
            acc.x += x * w.x; acc.y += x * w.y; acc.z += x * w.z; acc.w += x * w.w;
        }
        *(float4*)(&s_pu[(es * 16 + ks) * 128 + 4 * h4]) = acc;
    }
    __syncthreads();
    if (tid < 256) {
        int es = tid >> 7, h = tid & 127;
        int e = s_isel[es];
        float a = eb1[e * 128 + h];
        #pragma unroll
        for (int ks = 0; ks < 16; ++ks) a += s_pu[(es * 16 + ks) * 128 + h];
        ws[WS_U + (size_t)b * 256 + es * 128 + h] = a;
    }
}

// ---------------------------------------------------------------------------
// C: epilogue over transposed v. grid = 256 b x 4 quads, 256 thr;
// wave -> 64-gene tile, lane -> gene: coalesced v loads, LDS broadcasts,
// coalesced pred writes.
// ---------------------------------------------------------------------------
__global__ __launch_bounds__(256) void c_kernel(
    const float* __restrict__ eW2, const float* __restrict__ eb2,
    const float* __restrict__ ws, float* __restrict__ pred)
{
    __shared__ float s_u[256];
    __shared__ float s_w2[256];
    const int b = blockIdx.x >> 2, quad = blockIdx.x & 3, tid = threadIdx.x;

    const int ea = (int)ws[WS_SEL + b * 4 + 0];
    const int eb = (int)ws[WS_SEL + b * 4 + 1];
    const float gA = ws[WS_SEL + b * 4 + 2];
    const float gB = ws[WS_SEL + b * 4 + 3];
    const float bA = eb2[ea], bB = eb2[eb];

    s_u[tid] = ws[WS_U + (size_t)b * 256 + tid];
    s_w2[tid] = (tid < 128) ? eW2[ea * 128 + tid] : eW2[eb * 128 + (tid - 128)];
    __syncthreads();

    const int wv = tid >> 6, lane = tid & 63;
    const int tile = quad * 4 + wv;
    const float* vA = ws + WS_V + ((size_t)tile * 512 + ea * 128) * 64 + lane;
    const float* vB = ws + WS_V + ((size_t)tile * 512 + eb * 128) * 64 + lane;

    float dA = 0.f, dB = 0.f;
    #pragma unroll 8
    for (int h = 0; h < 128; ++h) {
        dA += fmaxf(s_u[h]       + vA[(size_t)h * 64], 0.f) * s_w2[h];
        dB += fmaxf(s_u[128 + h] + vB[(size_t)h * 64], 0.f) * s_w2[128 + h];
    }
    const int g = tile * 64 + lane;
    if (g < NG) pred[(size_t)b * NG + g] = gA * (dA + bA) + gB * (dB + bB);
}

// ---------------------------------------------------------------------------
extern "C" void kernel_launch(void* const* d_in, const int* in_sizes, int n_in,
                              void* d_out, int out_size, void* d_ws, size_t ws_size,
                              hipStream_t stream) {
    const float* drug  = (const float*)d_in[0];
    const float* gex   = (const float*)d_in[1];
    const float* idose = (const float*)d_in[2];
    const float* cW1 = (const float*)d_in[3];  const float* cb1 = (const float*)d_in[4];
    const float* cW2 = (const float*)d_in[5];  const float* cb2 = (const float*)d_in[6];
    const float* cW3 = (const float*)d_in[7];  const float* cb3 = (const float*)d_in[8];
    const float* dW1 = (const float*)d_in[9];  const float* db1 = (const float*)d_in[10];
    const float* dW2 = (const float*)d_in[11]; const float* db2 = (const float*)d_in[12];
    const float* gene = (const float*)d_in[13];
    const float* gW1 = (const float*)d_in[14]; const float* gb1 = (const float*)d_in[15];
    const float* gW2 = (const float*)d_in[16]; const float* gb2 = (const float*)d_in[17];
    const float* eW1 = (const float*)d_in[18]; const float* eb1 = (const float*)d_in[19];
    const float* eW2 = (const float*)d_in[20]; const float* eb2 = (const float*)d_in[21];

    float* ws   = (float*)d_ws;
    float* out  = (float*)d_out;
    float* pred = out;               // [B, G]
    float* cell = out + NB * NG;     // [B, 50]

    ab_kernel<<<AB_GRID, 1024, 0, stream>>>(drug, gex, idose,
        cW1, cb1, cW2, cb2, cW3, cb3, dW1, db1, dW2, db2,
        gW1, gb1, gW2, gb2, eW1, eb1, gene, ws, cell);
    c_kernel<<<NB * 4, 256, 0, stream>>>(eW2, eb2, ws, pred);
}